// Round 5
// baseline (178.510 us; speedup 1.0000x reference)
//
#include <hip/hip_runtime.h>
#include <math.h>

#define NHEAD 8
#define DIM   16
#define EPSF  1e-6f
#define KVCH  8          // L-chunks for kv partial reduction

typedef _Float16 half2_t __attribute__((ext_vector_type(2)));
typedef _Float16 half4_t __attribute__((ext_vector_type(4)));
typedef _Float16 half8_t __attribute__((ext_vector_type(8)));

#if defined(__has_builtin)
#if __has_builtin(__builtin_amdgcn_fdot2)
#define HAVE_FDOT2 1
#endif
#endif

__device__ __forceinline__ float dot2(half2_t a, half2_t b, float c) {
#ifdef HAVE_FDOT2
    return __builtin_amdgcn_fdot2(a, b, c, false);
#else
    return c + (float)a.x * (float)b.x + (float)a.y * (float)b.y;
#endif
}

// ---- solved_sample flag decode, robust to int32 / float32 / byte-bool marshalling.
__device__ __forceinline__ bool solved_flag(const void* p, int i) {
    const unsigned int* u = (const unsigned int*)p;
    unsigned int v0 = u[0];
    if (v0 <= 1u)             return u[i] != 0u;                   // int32 0/1
    if (v0 == 0x3F800000u)    return ((const float*)p)[i] != 0.0f; // float32
    return ((const unsigned char*)p)[i] != 0;                      // 1-byte bools
}

__device__ __forceinline__ float fm(float x) {           // elu(x)+1
    return x > 0.f ? x + 1.f : expf(x);
}

// ---- 3x3 inverse in double
__device__ void inv3d(const double* M, double* inv) {
    double det = M[0]*(M[4]*M[8]-M[5]*M[7]) - M[1]*(M[3]*M[8]-M[5]*M[6]) + M[2]*(M[3]*M[7]-M[4]*M[6]);
    double id = 1.0 / det;
    inv[0] =  (M[4]*M[8]-M[5]*M[7])*id;
    inv[1] = -(M[1]*M[8]-M[2]*M[7])*id;
    inv[2] =  (M[1]*M[5]-M[2]*M[4])*id;
    inv[3] = -(M[3]*M[8]-M[5]*M[6])*id;
    inv[4] =  (M[0]*M[8]-M[2]*M[6])*id;
    inv[5] = -(M[0]*M[5]-M[2]*M[3])*id;
    inv[6] =  (M[3]*M[7]-M[4]*M[6])*id;
    inv[7] = -(M[0]*M[7]-M[1]*M[6])*id;
    inv[8] =  (M[0]*M[4]-M[1]*M[3])*id;
}

__device__ void compute_F_one(const float* K0, const float* K1, const float* R,
                              const float* t, float invs, float* Fout, int n) {
    double A[9], B[9];
    for (int i = 0; i < 9; ++i) {
        float a = K0[n*9 + i], b = K1[n*9 + i];
        if (i < 6) { a *= invs; b *= invs; }   // rows 0,1 scaled
        A[i] = (double)a; B[i] = (double)b;
    }
    double iA[9], iB[9];
    inv3d(A, iA); inv3d(B, iB);
    double tx = t[n*3+0], ty = t[n*3+1], tz = t[n*3+2];
    double S[9] = {0.0,-tz,ty, tz,0.0,-tx, -ty,tx,0.0};
    double E[9], M[9];
    for (int i = 0; i < 3; ++i)
        for (int j = 0; j < 3; ++j) {
            double s = 0.0;
            for (int k = 0; k < 3; ++k) s += S[i*3+k] * (double)R[n*9 + k*3 + j];
            E[i*3+j] = s;
        }
    for (int i = 0; i < 3; ++i)
        for (int j = 0; j < 3; ++j) {
            double s = 0.0;
            for (int k = 0; k < 3; ++k) s += E[i*3+k] * iA[k*3+j];
            M[i*3+j] = s;
        }
    for (int i = 0; i < 3; ++i)
        for (int j = 0; j < 3; ++j) {
            double s = 0.0;
            for (int k = 0; k < 3; ++k) s += iB[k*3+i] * M[k*3+j];
            Fout[n*9 + i*3 + j] = (float)s;
        }
}

// ---- kernel 1: role-split blocks.
//   blocks [0, PB):      featmap K -> fp16 Kh, convert V -> fp16 Vh;
//                        block 0 also computes F and zero-fills the sentinel row
//   blocks [PB, PB+KB):  KV/Ksum chunk-partials for unsolved samples
__launch_bounds__(256)
__global__ void prep_kv(const float4* __restrict__ Kr4, const float4* __restrict__ Vr4,
                        _Float16* __restrict__ Kh, _Float16* __restrict__ Vh, int n4,
                        const float* __restrict__ Kr, const float* __restrict__ Vr,
                        const void* __restrict__ flags,
                        float* __restrict__ KVp, float* __restrict__ Ksp,
                        const float* __restrict__ K0, const float* __restrict__ K1,
                        const float* __restrict__ R,  const float* __restrict__ t,
                        const int* __restrict__ scale_p, float* __restrict__ Fout,
                        int N, int L, int PB) {
    if ((int)blockIdx.x < PB) {
        int i = blockIdx.x * 256 + threadIdx.x;
        if (i < n4) {
            float4 k = Kr4[i];
            half4_t kh = { (_Float16)fm(k.x), (_Float16)fm(k.y), (_Float16)fm(k.z), (_Float16)fm(k.w) };
            ((half4_t*)Kh)[i] = kh;
            float4 v = Vr4[i];
            half4_t vh = { (_Float16)v.x, (_Float16)v.y, (_Float16)v.z, (_Float16)v.w };
            ((half4_t*)Vh)[i] = vh;
        }
        if (blockIdx.x == 0) {
            if (threadIdx.x < (unsigned)N) {
                float invs = 1.0f / (float)(*scale_p);
                compute_F_one(K0, K1, R, t, invs, Fout, threadIdx.x);
            }
            // zero sentinel row at element offset N*L*128 in both Kh and Vh
            if (threadIdx.x >= 64 && threadIdx.x < 192) {
                int tz = threadIdx.x - 64;               // 0..127
                size_t zr = (size_t)N * L * 128 + tz;
                Kh[zr] = (_Float16)0.f;
                Vh[zr] = (_Float16)0.f;
            }
        }
    } else {
        int kb = blockIdx.x - PB;          // 0 .. N*NHEAD*KVCH-1
        int chunk = kb & (KVCH - 1);
        int h = (kb >> 3) & 7;
        int n = kb >> 6;
        if (n >= N || solved_flag(flags, n)) return;
        int tdx = threadIdx.x;
        int d = tdx >> 4, v = tdx & 15;
        int rowsPer = (L + KVCH - 1) / KVCH;
        int r0 = chunk * rowsPer;
        int r1 = min(r0 + rowsPer, L);
        const float* Kb = Kr + (size_t)n * L * (NHEAD * DIM) + h * DIM;
        const float* Vb = Vr + (size_t)n * L * (NHEAD * DIM) + h * DIM;
        float acc = 0.f, ks = 0.f;
        #pragma unroll 8
        for (int s = r0; s < r1; ++s) {
            float kd = fm(Kb[(size_t)s * (NHEAD * DIM) + d]);
            float vv = Vb[(size_t)s * (NHEAD * DIM) + v];
            acc += kd * vv;
            ks  += kd;
        }
        KVp[(((size_t)chunk * N + n) * NHEAD + h) * 256 + (d << 4) + v] = acc;
        if (v == 0) Ksp[(((size_t)chunk * N + n) * NHEAD + h) * 16 + d] = ks;
    }
}

// ---- kernel 2: fused solved-attention (2 waves/query, LDS candidate table,
//               zero-row sentinel) + unsolved epilogue
__launch_bounds__(256)
__global__ void mega(const float* __restrict__ Qr,
                     const _Float16* __restrict__ Kh, const _Float16* __restrict__ Vh,
                     const void* __restrict__ flags,  const float* __restrict__ F,
                     const float* __restrict__ KVp,   const float* __restrict__ Ksp,
                     float* __restrict__ outp,
                     const int* __restrict__ h0c_p, const int* __restrict__ w0c_p,
                     int N, int L, int Bs) {
    __shared__ int    tbl[4][96];
    __shared__ float2 comb[2][64];
    __shared__ float  dcomb[2][8];       // per-query-slot, PER-HEAD partial den
    if ((int)blockIdx.x < Bs) {
        // ------------- solved path: 2 waves per query, 2 queries per block -------------
        int w    = threadIdx.x >> 6;   // wave 0..3
        int p    = w & 1;              // parity within the query's wave pair
        int qp   = w >> 1;             // query slot in block (0/1)
        int lane = threadIdx.x & 63;
        int q    = blockIdx.x * 2 + qp;
        int n    = q / L;              // both queries of a block share n (L even)
        if (n >= N) return;
        if (!solved_flag(flags, n)) return;   // uniform across block: no barrier yet
        int NL = N * L;
        int s = q - n * L;
        int W  = *w0c_p;
        int Hc = *h0c_p;
        float px = (float)(s % W);
        float py = (float)(s / W);

        const float* Fn = F + n * 9;
        float a = Fn[0]*px + Fn[1]*py + Fn[2];
        float b = Fn[3]*px + Fn[4]*py + Fn[5];
        float c = Fn[6]*px + Fn[7]*py + Fn[8];
        float nrm = sqrtf(a*a + b*b);
        float mdiv = fmaxf(nrm, 1e-12f);
        a /= mdiv; b /= mdiv; c /= mdiv;
        bool mode = fabsf(b) >= fabsf(a);

        float slope, inter;
        int outerN, innerMax, sI, sO;
        if (mode) {
            float bs = (fabsf(b) < 1e-12f) ? 1e-12f : b;
            slope = -a / bs; inter = -c / bs;
            outerN = W; innerMax = Hc; sI = W; sO = 1;
        } else {
            float as = (fabsf(a) < 1e-12f) ? 1e-12f : a;
            slope = -b / as; inter = -c / as;
            outerN = Hc; innerMax = W; sI = 1; sO = W;
        }

        int c8 = lane >> 3;   // candidate sub-index 0..7 within this wave's group slice
        int h  = lane & 7;    // head
        int h16 = h << 4;

        // Q fragment -> fp16 pairs for fdot2
        const float4* q4 = (const float4*)(Qr + (size_t)q * (NHEAD * DIM) + h16);
        half2_t q2[8];
        {
            float4 a0 = q4[0], a1 = q4[1], a2 = q4[2], a3 = q4[3];
            q2[0] = (half2_t){ (_Float16)fm(a0.x), (_Float16)fm(a0.y) };
            q2[1] = (half2_t){ (_Float16)fm(a0.z), (_Float16)fm(a0.w) };
            q2[2] = (half2_t){ (_Float16)fm(a1.x), (_Float16)fm(a1.y) };
            q2[3] = (half2_t){ (_Float16)fm(a1.z), (_Float16)fm(a1.w) };
            q2[4] = (half2_t){ (_Float16)fm(a2.x), (_Float16)fm(a2.y) };
            q2[5] = (half2_t){ (_Float16)fm(a2.z), (_Float16)fm(a2.w) };
            q2[6] = (half2_t){ (_Float16)fm(a3.x), (_Float16)fm(a3.y) };
            q2[7] = (half2_t){ (_Float16)fm(a3.z), (_Float16)fm(a3.w) };
        }

        // ---- build this wave's 96-entry candidate table (validity baked via sentinel)
        int totalC = outerN * 3;
        int zsent  = NL << 7;                 // element offset of the zero row
        const float hw = 1.5f;
        for (int tt = lane; tt < 96; tt += 64) {
            int g = tt >> 3, c8t = tt & 7;
            int m = (g << 4) | (p << 3) | c8t;     // global candidate index
            int o = (int)((unsigned)m / 3u);
            int j = m - o * 3;
            float cc = fmaf(slope, (float)o, inter);
            float lo = cc - hw, hi = cc + hw;
            int ii = (int)floorf(lo) + 1 + j;
            float fi = (float)ii;
            bool valid = (m < totalC) && (ii >= 0) && (ii < innerMax)
                         && (fi > lo) && (fi < hi);
            int s2 = ii * sI + o * sO;
            valid = valid && (s2 != 0);            // reference's gather drops index 0
            tbl[w][tt] = valid ? ((n * L + s2) << 7) : zsent;
        }
        __syncthreads();

        half2_t acc2[8];
        #pragma unroll
        for (int i = 0; i < 8; ++i) acc2[i] = (half2_t){ (_Float16)0.f, (_Float16)0.f };
        float den = 0.f;

        int groups = (totalC + 15) >> 4;          // 16 candidates/group across the pair
        #pragma unroll 3
        for (int g = 0; g < groups; ++g) {
            int entry = tbl[w][(g << 3) + c8];    // 8-lane broadcast ds_read
            const half8_t* kr = (const half8_t*)(Kh + entry + h16);
            const half8_t* vr = (const half8_t*)(Vh + entry + h16);
            half8_t k0 = kr[0], k1 = kr[1];
            half8_t v0 = vr[0], v1 = vr[1];
            union H8 { half8_t v; half2_t h[4]; };
            H8 ku0, ku1, vu0, vu1;
            ku0.v = k0; ku1.v = k1; vu0.v = v0; vu1.v = v1;
            float sA = 0.f, sB = 0.f;
            sA = dot2(q2[0], ku0.h[0], sA);
            sB = dot2(q2[1], ku0.h[1], sB);
            sA = dot2(q2[2], ku0.h[2], sA);
            sB = dot2(q2[3], ku0.h[3], sB);
            sA = dot2(q2[4], ku1.h[0], sA);
            sB = dot2(q2[5], ku1.h[1], sB);
            sA = dot2(q2[6], ku1.h[2], sA);
            sB = dot2(q2[7], ku1.h[3], sB);
            float sc = sA + sB;                   // zero row -> exactly 0
            den += sc;
            _Float16 sch = (_Float16)sc;
            half2_t scv = (half2_t){ sch, sch };
            acc2[0] += scv * vu0.h[0];
            acc2[1] += scv * vu0.h[1];
            acc2[2] += scv * vu0.h[2];
            acc2[3] += scv * vu0.h[3];
            acc2[4] += scv * vu1.h[0];
            acc2[5] += scv * vu1.h[1];
            acc2[6] += scv * vu1.h[2];
            acc2[7] += scv * vu1.h[3];
        }

        // den: full butterfly across candidate lanes (bits 3,4,5) -> per-head sum
        den += __shfl_xor(den, 8);
        den += __shfl_xor(den, 16);
        den += __shfl_xor(den, 32);

        // acc: payload-halving butterfly
        bool hi8 = (lane & 8) != 0;
        half2_t t4[4];
        #pragma unroll
        for (int j2 = 0; j2 < 4; ++j2) {
            half2_t send = hi8 ? acc2[j2] : acc2[4 + j2];
            int rr = __shfl_xor(__builtin_bit_cast(int, send), 8);
            half2_t keep = hi8 ? acc2[4 + j2] : acc2[j2];
            t4[j2] = keep + __builtin_bit_cast(half2_t, rr);
        }
        bool hi16 = (lane & 16) != 0;
        half2_t t2[2];
        #pragma unroll
        for (int j2 = 0; j2 < 2; ++j2) {
            half2_t send = hi16 ? t4[j2] : t4[2 + j2];
            int rr = __shfl_xor(__builtin_bit_cast(int, send), 16);
            half2_t keep = hi16 ? t4[2 + j2] : t4[j2];
            t2[j2] = keep + __builtin_bit_cast(half2_t, rr);
        }
        bool hi32 = (lane & 32) != 0;
        half2_t t1;
        {
            half2_t send = hi32 ? t2[0] : t2[1];
            int rr = __shfl_xor(__builtin_bit_cast(int, send), 32);
            half2_t keep = hi32 ? t2[1] : t2[0];
            t1 = keep + __builtin_bit_cast(half2_t, rr);
        }
        int e0 = (hi8 ? 8 : 0) + (hi16 ? 4 : 0) + (hi32 ? 2 : 0);

        // ---- cross-wave combine (parity 1 publishes, parity 0 finalizes)
        if (p == 1) {
            comb[qp][lane] = make_float2((float)t1.x, (float)t1.y);
            if (lane < 8) dcomb[qp][lane] = den;   // lane == head for lanes 0..7
        }
        __syncthreads();
        if (p == 0) {
            float2 oth = comb[qp][lane];
            float dtot = den + dcomb[qp][h];       // per-head partial from parity 1
            float r = 1.0f / (dtot + EPSF);
            float2 o2 = { ((float)t1.x + oth.x) * r, ((float)t1.y + oth.y) * r };
            *(float2*)(outp + (size_t)q * (NHEAD * DIM) + h16 + e0) = o2;
        }
    } else {
        // ---------------- unsolved epilogue: out = Q.KV / (Q.Ksum + eps) ----------------
        long long tot2 = (long long)N * L * NHEAD * DIM / 2;
        long long idx2 = (long long)(blockIdx.x - Bs) * 256 + threadIdx.x;
        if (idx2 >= tot2) return;
        int pp = (int)(idx2 & 63);
        int h = pp >> 3;
        int v = (pp & 7) * 2;
        long long ns = idx2 >> 6;
        int n = (int)(ns / L);
        if (solved_flag(flags, n)) return;
        const float* qrow = Qr + ns * (NHEAD * DIM) + h * DIM;
        float num0 = 0.f, num1 = 0.f, den = 0.f;
        #pragma unroll
        for (int d = 0; d < 16; ++d) {
            float qd = fm(qrow[d]);
            #pragma unroll
            for (int cch = 0; cch < KVCH; ++cch) {
                const float2 kv2 = *(const float2*)(KVp + (((size_t)cch * N + n) * NHEAD + h) * 256 + (d << 4) + v);
                num0 += qd * kv2.x;
                num1 += qd * kv2.y;
                den  += qd * Ksp[(((size_t)cch * N + n) * NHEAD + h) * 16 + d];
            }
        }
        float rdiv = 1.0f / (den + EPSF);
        size_t ob = ns * (NHEAD * DIM) + h * DIM + v;
        outp[ob]     = num0 * rdiv;
        outp[ob + 1] = num1 * rdiv;
    }
}

extern "C" void kernel_launch(void* const* d_in, const int* in_sizes, int n_in,
                              void* d_out, int out_size, void* d_ws, size_t ws_size,
                              hipStream_t stream) {
    const float* Qr   = (const float*)d_in[0];
    const float* Kr   = (const float*)d_in[1];
    const float* Vr   = (const float*)d_in[2];
    const void*  flag = d_in[3];
    const float* K0   = (const float*)d_in[4];
    const float* K1   = (const float*)d_in[5];
    const float* R    = (const float*)d_in[6];
    const float* t    = (const float*)d_in[7];
    const int*   h0c  = (const int*)d_in[8];
    const int*   w0c  = (const int*)d_in[9];
    const int*   scl  = (const int*)d_in[10];

    int N = in_sizes[3];
    int T = in_sizes[0];                 // N*L*H*D
    int L = T / (N * NHEAD * DIM);

    size_t arr = (size_t)T + 8 * 128;                     // halves per array (+ sentinel rows)
    _Float16* Kh = (_Float16*)d_ws;
    _Float16* Vh = Kh + arr;
    float* Fm   = (float*)(Vh + arr);                     // N*9
    float* KVp  = Fm + (size_t)N * 9;                     // KVCH*N*H*256
    float* Ksp  = KVp + (size_t)KVCH * N * NHEAD * 256;   // KVCH*N*H*16

    float* outp = (float*)d_out;

    int n4 = T / 4;
    int PB = (n4 + 255) / 256;
    int KB = N * NHEAD * KVCH;
    prep_kv<<<PB + KB, 256, 0, stream>>>((const float4*)Kr, (const float4*)Vr,
                                         Kh, Vh, n4, Kr, Vr, flag, KVp, Ksp,
                                         K0, K1, R, t, scl, Fm, N, L, PB);

    int Bs = (N * L) / 2;                                 // 2 queries per block
    long long tot2 = (long long)N * L * NHEAD * DIM / 2;
    int Bu = (int)((tot2 + 255) / 256);
    mega<<<Bs + Bu, 256, 0, stream>>>(Qr, Kh, Vh, flag, Fm, KVp, Ksp, outp,
                                      h0c, w0c, N, L, Bs);
}

// Round 6
// 177.349 us; speedup vs baseline: 1.0066x; 1.0066x over previous
//
#include <hip/hip_runtime.h>
#include <math.h>

#define NHEAD 8
#define DIM   16
#define EPSF  1e-6f
#define KVCH  8          // L-chunks for kv partial reduction

typedef _Float16 half2_t __attribute__((ext_vector_type(2)));
typedef _Float16 half4_t __attribute__((ext_vector_type(4)));
typedef _Float16 half8_t __attribute__((ext_vector_type(8)));

#if defined(__has_builtin)
#if __has_builtin(__builtin_amdgcn_fdot2)
#define HAVE_FDOT2 1
#endif
#endif

__device__ __forceinline__ float dot2(half2_t a, half2_t b, float c) {
#ifdef HAVE_FDOT2
    return __builtin_amdgcn_fdot2(a, b, c, false);
#else
    return c + (float)a.x * (float)b.x + (float)a.y * (float)b.y;
#endif
}

// ---- solved_sample flag decode, robust to int32 / float32 / byte-bool marshalling.
__device__ __forceinline__ bool solved_flag(const void* p, int i) {
    const unsigned int* u = (const unsigned int*)p;
    unsigned int v0 = u[0];
    if (v0 <= 1u)             return u[i] != 0u;                   // int32 0/1
    if (v0 == 0x3F800000u)    return ((const float*)p)[i] != 0.0f; // float32
    return ((const unsigned char*)p)[i] != 0;                      // 1-byte bools
}

__device__ __forceinline__ float fm(float x) {           // elu(x)+1
    return x > 0.f ? x + 1.f : expf(x);
}

// ---- 3x3 inverse in double
__device__ void inv3d(const double* M, double* inv) {
    double det = M[0]*(M[4]*M[8]-M[5]*M[7]) - M[1]*(M[3]*M[8]-M[5]*M[6]) + M[2]*(M[3]*M[7]-M[4]*M[6]);
    double id = 1.0 / det;
    inv[0] =  (M[4]*M[8]-M[5]*M[7])*id;
    inv[1] = -(M[1]*M[8]-M[2]*M[7])*id;
    inv[2] =  (M[1]*M[5]-M[2]*M[4])*id;
    inv[3] = -(M[3]*M[8]-M[5]*M[6])*id;
    inv[4] =  (M[0]*M[8]-M[2]*M[6])*id;
    inv[5] = -(M[0]*M[5]-M[2]*M[3])*id;
    inv[6] =  (M[3]*M[7]-M[4]*M[6])*id;
    inv[7] = -(M[0]*M[7]-M[1]*M[6])*id;
    inv[8] =  (M[0]*M[4]-M[1]*M[3])*id;
}

__device__ void compute_F_one(const float* K0, const float* K1, const float* R,
                              const float* t, float invs, float* Fout, int n) {
    double A[9], B[9];
    for (int i = 0; i < 9; ++i) {
        float a = K0[n*9 + i], b = K1[n*9 + i];
        if (i < 6) { a *= invs; b *= invs; }   // rows 0,1 scaled
        A[i] = (double)a; B[i] = (double)b;
    }
    double iA[9], iB[9];
    inv3d(A, iA); inv3d(B, iB);
    double tx = t[n*3+0], ty = t[n*3+1], tz = t[n*3+2];
    double S[9] = {0.0,-tz,ty, tz,0.0,-tx, -ty,tx,0.0};
    double E[9], M[9];
    for (int i = 0; i < 3; ++i)
        for (int j = 0; j < 3; ++j) {
            double s = 0.0;
            for (int k = 0; k < 3; ++k) s += S[i*3+k] * (double)R[n*9 + k*3 + j];
            E[i*3+j] = s;
        }
    for (int i = 0; i < 3; ++i)
        for (int j = 0; j < 3; ++j) {
            double s = 0.0;
            for (int k = 0; k < 3; ++k) s += E[i*3+k] * iA[k*3+j];
            M[i*3+j] = s;
        }
    for (int i = 0; i < 3; ++i)
        for (int j = 0; j < 3; ++j) {
            double s = 0.0;
            for (int k = 0; k < 3; ++k) s += iB[k*3+i] * M[k*3+j];
            Fout[n*9 + i*3 + j] = (float)s;
        }
}

// ---- kernel 1: role-split blocks (featmap+F+sentinel | kv partials). Unchanged.
__launch_bounds__(256)
__global__ void prep_kv(const float4* __restrict__ Kr4, const float4* __restrict__ Vr4,
                        _Float16* __restrict__ Kh, _Float16* __restrict__ Vh, int n4,
                        const float* __restrict__ Kr, const float* __restrict__ Vr,
                        const void* __restrict__ flags,
                        float* __restrict__ KVp, float* __restrict__ Ksp,
                        const float* __restrict__ K0, const float* __restrict__ K1,
                        const float* __restrict__ R,  const float* __restrict__ t,
                        const int* __restrict__ scale_p, float* __restrict__ Fout,
                        int N, int L, int PB) {
    if ((int)blockIdx.x < PB) {
        int i = blockIdx.x * 256 + threadIdx.x;
        if (i < n4) {
            float4 k = Kr4[i];
            half4_t kh = { (_Float16)fm(k.x), (_Float16)fm(k.y), (_Float16)fm(k.z), (_Float16)fm(k.w) };
            ((half4_t*)Kh)[i] = kh;
            float4 v = Vr4[i];
            half4_t vh = { (_Float16)v.x, (_Float16)v.y, (_Float16)v.z, (_Float16)v.w };
            ((half4_t*)Vh)[i] = vh;
        }
        if (blockIdx.x == 0) {
            if (threadIdx.x < (unsigned)N) {
                float invs = 1.0f / (float)(*scale_p);
                compute_F_one(K0, K1, R, t, invs, Fout, threadIdx.x);
            }
            // zero sentinel row at element offset N*L*128 in both Kh and Vh
            if (threadIdx.x >= 64 && threadIdx.x < 192) {
                int tz = threadIdx.x - 64;               // 0..127
                size_t zr = (size_t)N * L * 128 + tz;
                Kh[zr] = (_Float16)0.f;
                Vh[zr] = (_Float16)0.f;
            }
        }
    } else {
        int kb = blockIdx.x - PB;          // 0 .. N*NHEAD*KVCH-1
        int chunk = kb & (KVCH - 1);
        int h = (kb >> 3) & 7;
        int n = kb >> 6;
        if (n >= N || solved_flag(flags, n)) return;
        int tdx = threadIdx.x;
        int d = tdx >> 4, v = tdx & 15;
        int rowsPer = (L + KVCH - 1) / KVCH;
        int r0 = chunk * rowsPer;
        int r1 = min(r0 + rowsPer, L);
        const float* Kb = Kr + (size_t)n * L * (NHEAD * DIM) + h * DIM;
        const float* Vb = Vr + (size_t)n * L * (NHEAD * DIM) + h * DIM;
        float acc = 0.f, ks = 0.f;
        #pragma unroll 8
        for (int s = r0; s < r1; ++s) {
            float kd = fm(Kb[(size_t)s * (NHEAD * DIM) + d]);
            float vv = Vb[(size_t)s * (NHEAD * DIM) + v];
            acc += kd * vv;
            ks  += kd;
        }
        KVp[(((size_t)chunk * N + n) * NHEAD + h) * 256 + (d << 4) + v] = acc;
        if (v == 0) Ksp[(((size_t)chunk * N + n) * NHEAD + h) * 16 + d] = ks;
    }
}

// ---- kernel 2: fused solved-attention (1 wave/query, lane-contiguous chunked
//               gather = minimal L1 granules, split-dot via shfl_xor(1)) + unsolved epilogue
__launch_bounds__(256)
__global__ void mega(const float* __restrict__ Qr,
                     const _Float16* __restrict__ Kh, const _Float16* __restrict__ Vh,
                     const void* __restrict__ flags,  const float* __restrict__ F,
                     const float* __restrict__ KVp,   const float* __restrict__ Ksp,
                     float* __restrict__ outp,
                     const int* __restrict__ h0c_p, const int* __restrict__ w0c_p,
                     int N, int L, int Bs) {
    __shared__ int tbl[4][192];   // per-wave candidate row BYTE offsets
    if ((int)blockIdx.x < Bs) {
        // ---------------- solved path: one wave per query, 4 queries/block ----------------
        int w    = threadIdx.x >> 6;
        int lane = threadIdx.x & 63;
        int q    = blockIdx.x * 4 + w;
        int n    = q / L;                 // uniform across block (L % 4 == 0)
        if (n >= N) return;
        if (!solved_flag(flags, n)) return;
        int NL = N * L;
        int s = q - n * L;
        int W  = *w0c_p;
        int Hc = *h0c_p;
        float px = (float)(s % W);
        float py = (float)(s / W);

        const float* Fn = F + n * 9;
        float a = Fn[0]*px + Fn[1]*py + Fn[2];
        float b = Fn[3]*px + Fn[4]*py + Fn[5];
        float c = Fn[6]*px + Fn[7]*py + Fn[8];
        float nrm = sqrtf(a*a + b*b);
        float mdiv = fmaxf(nrm, 1e-12f);
        a /= mdiv; b /= mdiv; c /= mdiv;
        bool mode = fabsf(b) >= fabsf(a);

        float slope, inter;
        int outerN, innerMax, sI, sO;
        if (mode) {
            float bs = (fabsf(b) < 1e-12f) ? 1e-12f : b;
            slope = -a / bs; inter = -c / bs;
            outerN = W; innerMax = Hc; sI = W; sO = 1;
        } else {
            float as = (fabsf(a) < 1e-12f) ? 1e-12f : a;
            slope = -b / as; inter = -c / as;
            outerN = Hc; innerMax = W; sI = 1; sO = W;
        }

        int c8 = lane >> 3;   // candidate sub-index 0..7
        int h  = lane & 7;    // chunk index: head h>>1 (half h&1) + head 4+(h>>1) (half h&1)

        // Q fragments this lane needs (fp32 -> fm -> fp16 pairs):
        //   lo: head h>>1,      dims [8*(h&1), +8)  = floats q*128 + 8h
        //   hi: head 4+(h>>1),  dims [8*(h&1), +8)  = floats q*128 + 64 + 8h
        const float4* qb = (const float4*)(Qr + (size_t)q * (NHEAD * DIM));
        half2_t ql[4], qh[4];
        {
            float4 a0 = qb[2*h], a1 = qb[2*h + 1];
            float4 b0 = qb[16 + 2*h], b1 = qb[16 + 2*h + 1];
            ql[0] = (half2_t){ (_Float16)fm(a0.x), (_Float16)fm(a0.y) };
            ql[1] = (half2_t){ (_Float16)fm(a0.z), (_Float16)fm(a0.w) };
            ql[2] = (half2_t){ (_Float16)fm(a1.x), (_Float16)fm(a1.y) };
            ql[3] = (half2_t){ (_Float16)fm(a1.z), (_Float16)fm(a1.w) };
            qh[0] = (half2_t){ (_Float16)fm(b0.x), (_Float16)fm(b0.y) };
            qh[1] = (half2_t){ (_Float16)fm(b0.z), (_Float16)fm(b0.w) };
            qh[2] = (half2_t){ (_Float16)fm(b1.x), (_Float16)fm(b1.y) };
            qh[3] = (half2_t){ (_Float16)fm(b1.z), (_Float16)fm(b1.w) };
        }

        // ---- build this wave's candidate table (byte offsets; invalid -> zero row)
        int totalC = outerN * 3;
        int zsent  = NL << 8;                 // BYTE offset of the zero sentinel row
        const float hw = 1.5f;
        for (int m = lane; m < 192; m += 64) {
            int o = (int)((unsigned)m / 3u);
            int j = m - o * 3;
            float cc = fmaf(slope, (float)o, inter);
            float lo = cc - hw, hi = cc + hw;
            int ii = (int)floorf(lo) + 1 + j;
            float fi = (float)ii;
            bool valid = (m < totalC) && (ii >= 0) && (ii < innerMax)
                         && (fi > lo) && (fi < hi);
            int s2 = ii * sI + o * sO;
            valid = valid && (s2 != 0);       // reference's gather drops index 0
            tbl[w][m] = valid ? ((n * L + s2) << 8) : zsent;
        }
        __syncthreads();

        half2_t accl[4], acch[4];
        #pragma unroll
        for (int i = 0; i < 4; ++i) {
            accl[i] = (half2_t){ (_Float16)0.f, (_Float16)0.f };
            acch[i] = (half2_t){ (_Float16)0.f, (_Float16)0.f };
        }
        float denl = 0.f, denh = 0.f;

        int groups = (totalC + 7) >> 3;       // 8 candidates per iteration
        int hoff = h << 4;                    // byte offset of chunk h within a row
        #pragma unroll 3
        for (int g = 0; g < groups; ++g) {
            int off = tbl[w][(g << 3) + c8];  // 8-lane broadcast ds_read
            const char* kp = (const char*)Kh + off + hoff;
            const char* vp = (const char*)Vh + off + hoff;
            half8_t klo = *(const half8_t*)kp;
            half8_t khi = *(const half8_t*)(kp + 128);
            half8_t vlo = *(const half8_t*)vp;
            half8_t vhi = *(const half8_t*)(vp + 128);
            union H8 { half8_t v; half2_t h[4]; };
            H8 kl, kh2, vl, vh2;
            kl.v = klo; kh2.v = khi; vl.v = vlo; vh2.v = vhi;
            float pl = 0.f, ph = 0.f;
            pl = dot2(ql[0], kl.h[0], pl);
            ph = dot2(qh[0], kh2.h[0], ph);
            pl = dot2(ql[1], kl.h[1], pl);
            ph = dot2(qh[1], kh2.h[1], ph);
            pl = dot2(ql[2], kl.h[2], pl);
            ph = dot2(qh[2], kh2.h[2], ph);
            pl = dot2(ql[3], kl.h[3], pl);
            ph = dot2(qh[3], kh2.h[3], ph);
            // combine half-dots across lane pair (h, h^1) -> full scores
            float sl = pl + __shfl_xor(pl, 1);
            float sh = ph + __shfl_xor(ph, 1);
            denl += sl;
            denh += sh;
            _Float16 slh = (_Float16)sl, shh = (_Float16)sh;
            half2_t slv = (half2_t){ slh, slh };
            half2_t shv = (half2_t){ shh, shh };
            accl[0] += slv * vl.h[0];  acch[0] += shv * vh2.h[0];
            accl[1] += slv * vl.h[1];  acch[1] += shv * vh2.h[1];
            accl[2] += slv * vl.h[2];  acch[2] += shv * vh2.h[2];
            accl[3] += slv * vl.h[3];  acch[3] += shv * vh2.h[3];
        }

        // ---- reduce across the 8 candidate groups (lanes differing in bits 3,4,5)
        #pragma unroll
        for (int off2 = 8; off2 < 64; off2 <<= 1) {
            denl += __shfl_xor(denl, off2);
            denh += __shfl_xor(denh, off2);
            #pragma unroll
            for (int i = 0; i < 4; ++i) {
                int rl = __shfl_xor(__builtin_bit_cast(int, accl[i]), off2);
                int rh = __shfl_xor(__builtin_bit_cast(int, acch[i]), off2);
                accl[i] += __builtin_bit_cast(half2_t, rl);
                acch[i] += __builtin_bit_cast(half2_t, rh);
            }
        }

        // ---- epilogue: lanes 0-7 write lo-head block, lanes 8-15 write hi-head block
        if (lane < 16) {
            int hh = lane & 7;
            bool hi = lane >= 8;
            half2_t a0 = hi ? acch[0] : accl[0];
            half2_t a1 = hi ? acch[1] : accl[1];
            half2_t a2 = hi ? acch[2] : accl[2];
            half2_t a3 = hi ? acch[3] : accl[3];
            float den = hi ? denh : denl;
            float r = 1.0f / (den + EPSF);
            float* op = outp + (size_t)q * (NHEAD * DIM) + (hi ? 64 : 0) + 8 * hh;
            float4 o0 = { (float)a0.x * r, (float)a0.y * r, (float)a1.x * r, (float)a1.y * r };
            float4 o1 = { (float)a2.x * r, (float)a2.y * r, (float)a3.x * r, (float)a3.y * r };
            *(float4*)op       = o0;
            *(float4*)(op + 4) = o1;
        }
    } else {
        // ---------------- unsolved epilogue: out = Q.KV / (Q.Ksum + eps) ----------------
        long long tot2 = (long long)N * L * NHEAD * DIM / 2;
        long long idx2 = (long long)(blockIdx.x - Bs) * 256 + threadIdx.x;
        if (idx2 >= tot2) return;
        int pp = (int)(idx2 & 63);
        int h = pp >> 3;
        int v = (pp & 7) * 2;
        long long ns = idx2 >> 6;
        int n = (int)(ns / L);
        if (solved_flag(flags, n)) return;
        const float* qrow = Qr + ns * (NHEAD * DIM) + h * DIM;
        float num0 = 0.f, num1 = 0.f, den = 0.f;
        #pragma unroll
        for (int d = 0; d < 16; ++d) {
            float qd = fm(qrow[d]);
            #pragma unroll
            for (int cch = 0; cch < KVCH; ++cch) {
                const float2 kv2 = *(const float2*)(KVp + (((size_t)cch * N + n) * NHEAD + h) * 256 + (d << 4) + v);
                num0 += qd * kv2.x;
                num1 += qd * kv2.y;
                den  += qd * Ksp[(((size_t)cch * N + n) * NHEAD + h) * 16 + d];
            }
        }
        float rdiv = 1.0f / (den + EPSF);
        size_t ob = ns * (NHEAD * DIM) + h * DIM + v;
        outp[ob]     = num0 * rdiv;
        outp[ob + 1] = num1 * rdiv;
    }
}

extern "C" void kernel_launch(void* const* d_in, const int* in_sizes, int n_in,
                              void* d_out, int out_size, void* d_ws, size_t ws_size,
                              hipStream_t stream) {
    const float* Qr   = (const float*)d_in[0];
    const float* Kr   = (const float*)d_in[1];
    const float* Vr   = (const float*)d_in[2];
    const void*  flag = d_in[3];
    const float* K0   = (const float*)d_in[4];
    const float* K1   = (const float*)d_in[5];
    const float* R    = (const float*)d_in[6];
    const float* t    = (const float*)d_in[7];
    const int*   h0c  = (const int*)d_in[8];
    const int*   w0c  = (const int*)d_in[9];
    const int*   scl  = (const int*)d_in[10];

    int N = in_sizes[3];
    int T = in_sizes[0];                 // N*L*H*D
    int L = T / (N * NHEAD * DIM);

    size_t arr = (size_t)T + 8 * 128;                     // halves per array (+ sentinel pad)
    _Float16* Kh = (_Float16*)d_ws;
    _Float16* Vh = Kh + arr;
    float* Fm   = (float*)(Vh + arr);                     // N*9
    float* KVp  = Fm + (size_t)N * 9;                     // KVCH*N*H*256
    float* Ksp  = KVp + (size_t)KVCH * N * NHEAD * 256;   // KVCH*N*H*16

    float* outp = (float*)d_out;

    int n4 = T / 4;
    int PB = (n4 + 255) / 256;
    int KB = N * NHEAD * KVCH;
    prep_kv<<<PB + KB, 256, 0, stream>>>((const float4*)Kr, (const float4*)Vr,
                                         Kh, Vh, n4, Kr, Vr, flag, KVp, Ksp,
                                         K0, K1, R, t, scl, Fm, N, L, PB);

    int Bs = (N * L) / 4;                                 // 4 queries per block, 1 wave each
    long long tot2 = (long long)N * L * NHEAD * DIM / 2;
    int Bu = (int)((tot2 + 255) / 256);
    mega<<<Bs + Bu, 256, 0, stream>>>(Qr, Kh, Vh, flag, Fm, KVp, Ksp, outp,
                                      h0c, w0c, N, L, Bs);
}